// Round 14
// baseline (140.713 us; speedup 1.0000x reference)
//
#include <hip/hip_runtime.h>
#include <hip/hip_bf16.h>
#include <cstdint>

#define LN2F 0.69314718056f

__device__ __forceinline__ float ssp(float x) {
    return fmaxf(x, 0.0f) + log1pf(expf(-fabsf(x))) - LN2F;
}

__device__ __forceinline__ uint16_t f2bf_rne(float x) {
    uint32_t u = __float_as_uint(x);
    u += 0x7FFF + ((u >> 16) & 1u);
    return (uint16_t)(u >> 16);
}

__device__ __forceinline__ float bf_lo(uint32_t u) { return __uint_as_float(u << 16); }
__device__ __forceinline__ float bf_hi(uint32_t u) { return __uint_as_float(u & 0xffff0000u); }

// ---------------------------------------------------------------------------
// prep: blocks [0,256):   v1 = (m*(v@W_a1)+b_a1)*m   (8 rows/block)
//       blocks [256,768): table T[g][d] = F(g*0.0025)[d] bf16 (8 g/block)
//       blocks [768,776): transpose W_a2/W_a3 -> Wt[col][k] (LDS-tile)
// ---------------------------------------------------------------------------
__global__ __launch_bounds__(512) void prep_kernel(
    const float* __restrict__ v, const float* __restrict__ mask,
    const float* __restrict__ W_a1, const float* __restrict__ b_a1,
    const float* __restrict__ W_s1, const float* __restrict__ b_s1,
    const float* __restrict__ W_s2, const float* __restrict__ b_s2,
    const float* __restrict__ W_a2, const float* __restrict__ W_a3,
    float* __restrict__ v1, uint16_t* __restrict__ T,
    float* __restrict__ Wt2, float* __restrict__ Wt3) {
    __shared__ float sA[8][304];
    __shared__ float sB[8][64];
    __shared__ float tile[64][65];
    const int t = threadIdx.x;

    if (blockIdx.x < 256) {
        const int r0 = blockIdx.x * 8;
        for (int e = t; e < 2048; e += 512) {
            int row = e >> 8, c = e & 255;
            sA[row][c] = v[(r0 + row) * 256 + c];
        }
        __syncthreads();
        const int col = t & 255;
        const int g = t >> 8;
        const int c0 = blockIdx.x & 15;
        float acc[4] = {0.f, 0.f, 0.f, 0.f};
        float w[16], wn[16];
        {
            const int kt = c0 * 16;
            #pragma unroll
            for (int q = 0; q < 16; ++q) w[q] = W_a1[(kt + q) * 256 + col];
        }
        for (int i = 0; i < 16; ++i) {
            const int kt = ((c0 + i) & 15) * 16;
            if (i < 15) {
                const int ktn = ((c0 + i + 1) & 15) * 16;
                #pragma unroll
                for (int q = 0; q < 16; ++q) wn[q] = W_a1[(ktn + q) * 256 + col];
            }
            #pragma unroll
            for (int q4 = 0; q4 < 4; ++q4) {
                const int k = kt + q4 * 4;
                const float w0 = w[q4 * 4 + 0], w1 = w[q4 * 4 + 1];
                const float w2 = w[q4 * 4 + 2], w3 = w[q4 * 4 + 3];
                #pragma unroll
                for (int rr = 0; rr < 4; ++rr) {
                    const float4 xv = *(const float4*)&sA[g * 4 + rr][k];
                    float a = acc[rr];
                    a = fmaf(xv.x, w0, a);
                    a = fmaf(xv.y, w1, a);
                    a = fmaf(xv.z, w2, a);
                    a = fmaf(xv.w, w3, a);
                    acc[rr] = a;
                }
            }
            if (i < 15) {
                #pragma unroll
                for (int q = 0; q < 16; ++q) w[q] = wn[q];
            }
        }
        const float b = b_a1[col];
        #pragma unroll
        for (int rr = 0; rr < 4; ++rr) {
            const int r = r0 + g * 4 + rr;
            const float m = mask[r];
            v1[r * 256 + col] = (acc[rr] * m + b) * m;
        }
    } else if (blockIdx.x < 768) {
        const int g0 = (blockIdx.x - 256) * 8;
        #pragma unroll
        for (int gg = 0; gg < 8; ++gg) {
            if (t < 300) {
                float d = (float)(g0 + gg) * 0.0025f;
                float diff = d - 0.1f * (float)t;
                sA[gg][t] = expf(-10.f * diff * diff);
            }
        }
        __syncthreads();
        {   // h = ssp(rbf @ W_s1 + b_s1), 4-way ILP
            int gg = t >> 6, c = t & 63;
            float a0 = 0.f, a1 = 0.f, a2 = 0.f, a3 = 0.f;
            for (int r = 0; r < 300; r += 4) {
                a0 = fmaf(sA[gg][r + 0], W_s1[(r + 0) * 64 + c], a0);
                a1 = fmaf(sA[gg][r + 1], W_s1[(r + 1) * 64 + c], a1);
                a2 = fmaf(sA[gg][r + 2], W_s1[(r + 2) * 64 + c], a2);
                a3 = fmaf(sA[gg][r + 3], W_s1[(r + 3) * 64 + c], a3);
            }
            sB[gg][c] = ssp(b_s1[c] + ((a0 + a1) + (a2 + a3)));
        }
        __syncthreads();
        {
            int col = t & 255, glo = t >> 8;
            float bb = b_s2[col];
            float val[4];
            #pragma unroll
            for (int q = 0; q < 4; ++q) val[q] = bb;
            for (int c = 0; c < 64; ++c) {
                float w = W_s2[c * 256 + col];
                #pragma unroll
                for (int q = 0; q < 4; ++q)
                    val[q] = fmaf(sB[glo + 2 * q][c], w, val[q]);
            }
            #pragma unroll
            for (int q = 0; q < 4; ++q) {
                int g = g0 + glo + 2 * q;
                T[g * 256 + col] = f2bf_rne(ssp(val[q]));
            }
        }
    } else {
        // ---- transpose 64-col stripe of W_a2/W_a3 into Wt[col][k] ----
        const int blk = blockIdx.x - 768;          // 0..7
        const float* Wsrc = (blk < 4) ? W_a2 : W_a3;
        float* Wdst = (blk < 4) ? Wt2 : Wt3;
        const int c0 = (blk & 3) * 64;
        for (int k0 = 0; k0 < 256; k0 += 64) {
            #pragma unroll
            for (int p = 0; p < 8; ++p) {        // load coalesced: W[k][c]
                int e = t + p * 512;
                int ki = e >> 6, ci = e & 63;
                tile[ki][ci] = Wsrc[(k0 + ki) * 256 + c0 + ci];
            }
            __syncthreads();
            #pragma unroll
            for (int p = 0; p < 8; ++p) {        // store coalesced: Wt[c][k]
                int e = t + p * 512;
                int ci = e >> 6, ki = e & 63;
                Wdst[(c0 + ci) * 256 + k0 + ki] = tile[ki][ci];
            }
            __syncthreads();
        }
    }
}

// ---------------------------------------------------------------------------
// main: 512 blocks x 512 thr, 4 rows/block, double-buffered v1 staging.
// Gather: wave w = (row = w>>1, h = w&1); lane l owns dims 4l..4l+3;
//   wave processes jj in [16h, 16h+16) of every 32-j tile (both waves always
//   active). Per j: 1 uint2 table load + 1 ds_read_b128 + 4 FMA.
//   Final LDS reduce of the two j-half partials (aliased onto dead v1s).
// Linears: col-split 2 rows/thread, transposed weights (float4 loads).
// ---------------------------------------------------------------------------
__global__ __launch_bounds__(512) void main_kernel(
    const float* __restrict__ dist, const float* __restrict__ v1,
    const uint16_t* __restrict__ T, const float* __restrict__ mask,
    const float* __restrict__ Wt2, const float* __restrict__ b_a2,
    const float* __restrict__ Wt3, const float* __restrict__ b_a3,
    float* __restrict__ out) {
    __shared__ float v1s[2][32][256];  // 64 KB double-buffered j-tile
    __shared__ uint32_t sk[4][256];    // 4 KB table byte offsets
    __shared__ float xs[4][256];       // 4 KB activations
    const int t = threadIdx.x;
    const int r0 = blockIdx.x * 4;
    const int b = r0 >> 8;
    const int w = t >> 6;              // wave 0..7
    const int l = t & 63;
    const int row = w >> 1;            // 0..3
    const int h = w & 1;               // j-half within tile

    #pragma unroll
    for (int it = 0; it < 2; ++it) {
        int e = t + it * 512;
        int rr = e >> 8, j = e & 255;
        float d = dist[(size_t)(r0 + rr) * 256 + j];
        int k = (int)fmaf(d, 400.f, 0.5f);   // nearest grid point, step 0.0025
        sk[rr][j] = (uint32_t)(min(k, 4095) << 9);
    }

    float4 acc = make_float4(0.f, 0.f, 0.f, 0.f);
    const char* Tp = (const char*)T + (l << 3);   // lane's 4 dims = 8 bytes
    const float4* srcbase = (const float4*)(v1 + ((size_t)b << 16));

    {   // stage tile 0
        const float4* src = srcbase;
        float4* dst = (float4*)v1s[0];
        #pragma unroll
        for (int u = 0; u < 4; ++u)
            dst[u * 512 + t] = src[u * 512 + t];
    }
    __syncthreads();   // covers sk + tile 0

    for (int jt = 0; jt < 256; jt += 32) {
        const int cur = (jt >> 5) & 1;
        float4 pf[4];
        const bool more = (jt + 32) < 256;
        if (more) {
            const float4* src = srcbase + (jt + 32) * 64;
            #pragma unroll
            for (int u = 0; u < 4; ++u)
                pf[u] = src[u * 512 + t];
        }
        const float (*vt)[256] = v1s[cur];
        const int jb = h << 4;             // this wave's 16-j chunk
        #pragma unroll
        for (int q4 = 0; q4 < 4; ++q4) {
            const uint4 kk = *(const uint4*)&sk[row][jt + jb + (q4 << 2)];
            const uint32_t ka[4] = {kk.x, kk.y, kk.z, kk.w};
            #pragma unroll
            for (int u = 0; u < 4; ++u) {
                const uint2 tu = *(const uint2*)(Tp + ka[u]);
                const float4 vv = *(const float4*)&vt[jb + (q4 << 2) + u][l << 2];
                acc.x = fmaf(bf_lo(tu.x), vv.x, acc.x);
                acc.y = fmaf(bf_hi(tu.x), vv.y, acc.y);
                acc.z = fmaf(bf_lo(tu.y), vv.z, acc.z);
                acc.w = fmaf(bf_hi(tu.y), vv.w, acc.w);
            }
        }
        if (more) {
            float4* dst = (float4*)v1s[cur ^ 1];
            #pragma unroll
            for (int u = 0; u < 4; ++u)
                dst[u * 512 + t] = pf[u];
        }
        __syncthreads();
    }
    {   // reduce j-half partials (alias red onto dead v1s[0])
        float4* red = (float4*)v1s;
        red[w * 64 + l] = acc;
        __syncthreads();
        if (t < 256) {
            const int rr = t >> 6, ll = t & 63;
            const float4 s0 = red[(2 * rr) * 64 + ll];
            const float4 s1 = red[(2 * rr + 1) * 64 + ll];
            const float m = mask[r0 + rr];
            *(float4*)&xs[rr][ll << 2] = make_float4(
                (s0.x + s1.x) * m, (s0.y + s1.y) * m,
                (s0.z + s1.z) * m, (s0.w + s1.w) * m);
        }
    }
    __syncthreads();

    // ---------------- a2 then a3 (col-split, transposed weights) ----------------
    const int col = t & 255;
    const int gg = t >> 8;               // rows 2gg, 2gg+1
    const int rA = r0 + 2 * gg, rB = rA + 1;
    const int rot = (blockIdx.x & 15) << 2;

    float a0 = 0.f, a1 = 0.f;
    {
        const float* Wr = Wt2 + col * 256;
        #pragma unroll 4
        for (int i = 0; i < 64; ++i) {
            const int k = (((i + rot) & 63) << 2);
            const float4 wq = *(const float4*)&Wr[k];
            const float4 xA = *(const float4*)&xs[2 * gg][k];
            const float4 xB = *(const float4*)&xs[2 * gg + 1][k];
            a0 = fmaf(xA.x, wq.x, a0); a0 = fmaf(xA.y, wq.y, a0);
            a0 = fmaf(xA.z, wq.z, a0); a0 = fmaf(xA.w, wq.w, a0);
            a1 = fmaf(xB.x, wq.x, a1); a1 = fmaf(xB.y, wq.y, a1);
            a1 = fmaf(xB.z, wq.z, a1); a1 = fmaf(xB.w, wq.w, a1);
        }
    }
    const float b2 = b_a2[col];
    const float y0 = ssp(a0 + b2) * mask[rA];
    const float y1 = ssp(a1 + b2) * mask[rB];
    __syncthreads();
    xs[2 * gg][col] = y0;
    xs[2 * gg + 1][col] = y1;
    __syncthreads();

    float c0a = 0.f, c1a = 0.f;
    {
        const float* Wr = Wt3 + col * 256;
        #pragma unroll 4
        for (int i = 0; i < 64; ++i) {
            const int k = (((i + rot) & 63) << 2);
            const float4 wq = *(const float4*)&Wr[k];
            const float4 xA = *(const float4*)&xs[2 * gg][k];
            const float4 xB = *(const float4*)&xs[2 * gg + 1][k];
            c0a = fmaf(xA.x, wq.x, c0a); c0a = fmaf(xA.y, wq.y, c0a);
            c0a = fmaf(xA.z, wq.z, c0a); c0a = fmaf(xA.w, wq.w, c0a);
            c1a = fmaf(xB.x, wq.x, c1a); c1a = fmaf(xB.y, wq.y, c1a);
            c1a = fmaf(xB.z, wq.z, c1a); c1a = fmaf(xB.w, wq.w, c1a);
        }
    }
    const float b3 = b_a3[col];
    out[(size_t)rA * 256 + col] = (c0a + b3) * mask[rA];
    out[(size_t)rB * 256 + col] = (c1a + b3) * mask[rB];
}

// ---------------------------------------------------------------------------
extern "C" void kernel_launch(void* const* d_in, const int* in_sizes, int n_in,
                              void* d_out, int out_size, void* d_ws, size_t ws_size,
                              hipStream_t stream) {
    const float* v    = (const float*)d_in[0];
    const float* dist = (const float*)d_in[1];
    const float* mask = (const float*)d_in[2];
    const float* W_s1 = (const float*)d_in[3];
    const float* b_s1 = (const float*)d_in[4];
    const float* W_s2 = (const float*)d_in[5];
    const float* b_s2 = (const float*)d_in[6];
    const float* W_a1 = (const float*)d_in[7];
    const float* b_a1 = (const float*)d_in[8];
    const float* W_a2 = (const float*)d_in[9];
    const float* b_a2 = (const float*)d_in[10];
    const float* W_a3 = (const float*)d_in[11];
    const float* b_a3 = (const float*)d_in[12];
    float* out = (float*)d_out;

    char* ws = (char*)d_ws;
    float*    v1  = (float*)(ws);                              // 2 MB
    uint16_t* T   = (uint16_t*)(ws + (2u << 20));              // 2 MB bf16 [4096][256]
    float*    Wt2 = (float*)(ws + (4u << 20));                 // 256 KB W_a2^T
    float*    Wt3 = (float*)(ws + (4u << 20) + (1u << 18));    // 256 KB W_a3^T

    prep_kernel<<<776, 512, 0, stream>>>(v, mask, W_a1, b_a1, W_s1, b_s1,
                                         W_s2, b_s2, W_a2, W_a3, v1, T, Wt2, Wt3);
    main_kernel<<<512, 512, 0, stream>>>(dist, v1, T, mask, Wt2, b_a2, Wt3, b_a3, out);
}

// Round 15
// 99.689 us; speedup vs baseline: 1.4115x; 1.4115x over previous
//
#include <hip/hip_runtime.h>
#include <hip/hip_bf16.h>
#include <cstdint>

#define LN2F 0.69314718056f

__device__ __forceinline__ float ssp(float x) {
    return fmaxf(x, 0.0f) + log1pf(expf(-fabsf(x))) - LN2F;
}

__device__ __forceinline__ uint16_t f2bf_rne(float x) {
    uint32_t u = __float_as_uint(x);
    u += 0x7FFF + ((u >> 16) & 1u);
    return (uint16_t)(u >> 16);
}

__device__ __forceinline__ float bf_lo(uint32_t u) { return __uint_as_float(u << 16); }
__device__ __forceinline__ float bf_hi(uint32_t u) { return __uint_as_float(u & 0xffff0000u); }

// ---------------------------------------------------------------------------
// prep: blocks [0,256): v1 = (m*(v@W_a1)+b_a1)*m   (8 rows/block)
//       blocks [256,768): table T[g][d] = F(g*0.0025)[d] bf16 (8 g/block)
// ---------------------------------------------------------------------------
__global__ __launch_bounds__(512) void prep_kernel(
    const float* __restrict__ v, const float* __restrict__ mask,
    const float* __restrict__ W_a1, const float* __restrict__ b_a1,
    const float* __restrict__ W_s1, const float* __restrict__ b_s1,
    const float* __restrict__ W_s2, const float* __restrict__ b_s2,
    float* __restrict__ v1, uint16_t* __restrict__ T) {
    __shared__ float sA[8][304];
    __shared__ float sB[8][64];
    const int t = threadIdx.x;

    if (blockIdx.x < 256) {
        const int r0 = blockIdx.x * 8;
        for (int e = t; e < 2048; e += 512) {
            int row = e >> 8, c = e & 255;
            sA[row][c] = v[(r0 + row) * 256 + c];
        }
        __syncthreads();
        const int col = t & 255;
        const int g = t >> 8;
        const int c0 = blockIdx.x & 15;
        float acc[4] = {0.f, 0.f, 0.f, 0.f};
        float w[16], wn[16];
        {
            const int kt = c0 * 16;
            #pragma unroll
            for (int q = 0; q < 16; ++q) w[q] = W_a1[(kt + q) * 256 + col];
        }
        for (int i = 0; i < 16; ++i) {
            const int kt = ((c0 + i) & 15) * 16;
            if (i < 15) {
                const int ktn = ((c0 + i + 1) & 15) * 16;
                #pragma unroll
                for (int q = 0; q < 16; ++q) wn[q] = W_a1[(ktn + q) * 256 + col];
            }
            #pragma unroll
            for (int q4 = 0; q4 < 4; ++q4) {
                const int k = kt + q4 * 4;
                const float w0 = w[q4 * 4 + 0], w1 = w[q4 * 4 + 1];
                const float w2 = w[q4 * 4 + 2], w3 = w[q4 * 4 + 3];
                #pragma unroll
                for (int rr = 0; rr < 4; ++rr) {
                    const float4 xv = *(const float4*)&sA[g * 4 + rr][k];
                    float a = acc[rr];
                    a = fmaf(xv.x, w0, a);
                    a = fmaf(xv.y, w1, a);
                    a = fmaf(xv.z, w2, a);
                    a = fmaf(xv.w, w3, a);
                    acc[rr] = a;
                }
            }
            if (i < 15) {
                #pragma unroll
                for (int q = 0; q < 16; ++q) w[q] = wn[q];
            }
        }
        const float b = b_a1[col];
        #pragma unroll
        for (int rr = 0; rr < 4; ++rr) {
            const int r = r0 + g * 4 + rr;
            const float m = mask[r];
            v1[r * 256 + col] = (acc[rr] * m + b) * m;
        }
    } else {
        const int g0 = (blockIdx.x - 256) * 8;
        #pragma unroll
        for (int gg = 0; gg < 8; ++gg) {
            if (t < 300) {
                float d = (float)(g0 + gg) * 0.0025f;
                float diff = d - 0.1f * (float)t;
                sA[gg][t] = expf(-10.f * diff * diff);
            }
        }
        __syncthreads();
        {   // h = ssp(rbf @ W_s1 + b_s1), 4-way ILP
            int gg = t >> 6, c = t & 63;
            float a0 = 0.f, a1 = 0.f, a2 = 0.f, a3 = 0.f;
            for (int r = 0; r < 300; r += 4) {
                a0 = fmaf(sA[gg][r + 0], W_s1[(r + 0) * 64 + c], a0);
                a1 = fmaf(sA[gg][r + 1], W_s1[(r + 1) * 64 + c], a1);
                a2 = fmaf(sA[gg][r + 2], W_s1[(r + 2) * 64 + c], a2);
                a3 = fmaf(sA[gg][r + 3], W_s1[(r + 3) * 64 + c], a3);
            }
            sB[gg][c] = ssp(b_s1[c] + ((a0 + a1) + (a2 + a3)));
        }
        __syncthreads();
        {
            int col = t & 255, glo = t >> 8;
            float bb = b_s2[col];
            float val[4];
            #pragma unroll
            for (int q = 0; q < 4; ++q) val[q] = bb;
            for (int c = 0; c < 64; ++c) {
                float w = W_s2[c * 256 + col];
                #pragma unroll
                for (int q = 0; q < 4; ++q)
                    val[q] = fmaf(sB[glo + 2 * q][c], w, val[q]);
            }
            #pragma unroll
            for (int q = 0; q < 4; ++q) {
                int g = g0 + glo + 2 * q;
                T[g * 256 + col] = f2bf_rne(ssp(val[q]));
            }
        }
    }
}

// ---------------------------------------------------------------------------
// main: 512 blocks x 512 thr, 4 rows/block, double-buffered v1 staging.
// Gather (R13 form): wave w = (row = w>>1, h = w&1); lane l owns dims
//   4l..4l+3; wave processes jj in [16h, 16h+16) of every 32-j tile.
//   Per j: 1 uint2 table load + 1 ds_read_b128 + 4 FMA. LDS reduce at end.
// Linears (R11 form): col-split 2 rows/thread, W[k][col] coalesced stream
//   with 16-deep prefetch + per-block chunk rotation.
// ---------------------------------------------------------------------------
__global__ __launch_bounds__(512) void main_kernel(
    const float* __restrict__ dist, const float* __restrict__ v1,
    const uint16_t* __restrict__ T, const float* __restrict__ mask,
    const float* __restrict__ W_a2, const float* __restrict__ b_a2,
    const float* __restrict__ W_a3, const float* __restrict__ b_a3,
    float* __restrict__ out) {
    __shared__ float v1s[2][32][256];  // 64 KB double-buffered j-tile
    __shared__ uint32_t sk[4][256];    // 4 KB table byte offsets
    __shared__ float xs[4][256];       // 4 KB activations
    const int t = threadIdx.x;
    const int r0 = blockIdx.x * 4;
    const int b = r0 >> 8;
    const int w = t >> 6;              // wave 0..7
    const int l = t & 63;
    const int row = w >> 1;            // 0..3
    const int h = w & 1;               // j-half within tile

    #pragma unroll
    for (int it = 0; it < 2; ++it) {
        int e = t + it * 512;
        int rr = e >> 8, j = e & 255;
        float d = dist[(size_t)(r0 + rr) * 256 + j];
        int k = (int)fmaf(d, 400.f, 0.5f);   // nearest grid point, step 0.0025
        sk[rr][j] = (uint32_t)(min(k, 4095) << 9);
    }

    float4 acc = make_float4(0.f, 0.f, 0.f, 0.f);
    const char* Tp = (const char*)T + (l << 3);   // lane's 4 dims = 8 bytes
    const float4* srcbase = (const float4*)(v1 + ((size_t)b << 16));

    {   // stage tile 0
        const float4* src = srcbase;
        float4* dst = (float4*)v1s[0];
        #pragma unroll
        for (int u = 0; u < 4; ++u)
            dst[u * 512 + t] = src[u * 512 + t];
    }
    __syncthreads();   // covers sk + tile 0

    for (int jt = 0; jt < 256; jt += 32) {
        const int cur = (jt >> 5) & 1;
        float4 pf[4];
        const bool more = (jt + 32) < 256;
        if (more) {   // issue next-tile loads early
            const float4* src = srcbase + (jt + 32) * 64;
            #pragma unroll
            for (int u = 0; u < 4; ++u)
                pf[u] = src[u * 512 + t];
        }
        const float (*vt)[256] = v1s[cur];
        const int jb = h << 4;             // this wave's 16-j chunk
        #pragma unroll
        for (int q4 = 0; q4 < 4; ++q4) {
            const uint4 kk = *(const uint4*)&sk[row][jt + jb + (q4 << 2)];
            const uint32_t ka[4] = {kk.x, kk.y, kk.z, kk.w};
            #pragma unroll
            for (int u = 0; u < 4; ++u) {
                const uint2 tu = *(const uint2*)(Tp + ka[u]);
                const float4 vv = *(const float4*)&vt[jb + (q4 << 2) + u][l << 2];
                acc.x = fmaf(bf_lo(tu.x), vv.x, acc.x);
                acc.y = fmaf(bf_hi(tu.x), vv.y, acc.y);
                acc.z = fmaf(bf_lo(tu.y), vv.z, acc.z);
                acc.w = fmaf(bf_hi(tu.y), vv.w, acc.w);
            }
        }
        if (more) {
            float4* dst = (float4*)v1s[cur ^ 1];
            #pragma unroll
            for (int u = 0; u < 4; ++u)
                dst[u * 512 + t] = pf[u];
        }
        __syncthreads();
    }
    {   // reduce j-half partials (aliased onto dead v1s)
        float4* red = (float4*)v1s;
        red[w * 64 + l] = acc;
        __syncthreads();
        if (t < 256) {
            const int rr = t >> 6, ll = t & 63;
            const float4 s0 = red[(2 * rr) * 64 + ll];
            const float4 s1 = red[(2 * rr + 1) * 64 + ll];
            const float m = mask[r0 + rr];
            *(float4*)&xs[rr][ll << 2] = make_float4(
                (s0.x + s1.x) * m, (s0.y + s1.y) * m,
                (s0.z + s1.z) * m, (s0.w + s1.w) * m);
        }
    }
    __syncthreads();

    // ---------------- a2 then a3 (col-split, 2 rows/thread) ----------------
    const int col = t & 255;
    const int gg = t >> 8;               // rows 2gg, 2gg+1
    const int rA = r0 + 2 * gg, rB = rA + 1;
    const int c0 = blockIdx.x & 15;

    float a0 = 0.f, a1 = 0.f;
    {
        float wv[16], wn[16];
        {
            const int kt = c0 * 16;
            #pragma unroll
            for (int q = 0; q < 16; ++q) wv[q] = W_a2[(kt + q) * 256 + col];
        }
        for (int i = 0; i < 16; ++i) {
            const int kt = ((c0 + i) & 15) * 16;
            if (i < 15) {
                const int ktn = ((c0 + i + 1) & 15) * 16;
                #pragma unroll
                for (int q = 0; q < 16; ++q) wn[q] = W_a2[(ktn + q) * 256 + col];
            }
            #pragma unroll
            for (int q4 = 0; q4 < 4; ++q4) {
                const int k = kt + (q4 << 2);
                const float4 xA = *(const float4*)&xs[2 * gg][k];
                const float4 xB = *(const float4*)&xs[2 * gg + 1][k];
                const float w0 = wv[q4 * 4 + 0], w1 = wv[q4 * 4 + 1];
                const float w2 = wv[q4 * 4 + 2], w3 = wv[q4 * 4 + 3];
                a0 = fmaf(xA.x, w0, a0); a0 = fmaf(xA.y, w1, a0);
                a0 = fmaf(xA.z, w2, a0); a0 = fmaf(xA.w, w3, a0);
                a1 = fmaf(xB.x, w0, a1); a1 = fmaf(xB.y, w1, a1);
                a1 = fmaf(xB.z, w2, a1); a1 = fmaf(xB.w, w3, a1);
            }
            if (i < 15) {
                #pragma unroll
                for (int q = 0; q < 16; ++q) wv[q] = wn[q];
            }
        }
    }
    const float b2 = b_a2[col];
    const float y0 = ssp(a0 + b2) * mask[rA];
    const float y1 = ssp(a1 + b2) * mask[rB];
    __syncthreads();
    xs[2 * gg][col] = y0;
    xs[2 * gg + 1][col] = y1;
    __syncthreads();

    float c0a = 0.f, c1a = 0.f;
    {
        float wv[16], wn[16];
        {
            const int kt = c0 * 16;
            #pragma unroll
            for (int q = 0; q < 16; ++q) wv[q] = W_a3[(kt + q) * 256 + col];
        }
        for (int i = 0; i < 16; ++i) {
            const int kt = ((c0 + i) & 15) * 16;
            if (i < 15) {
                const int ktn = ((c0 + i + 1) & 15) * 16;
                #pragma unroll
                for (int q = 0; q < 16; ++q) wn[q] = W_a3[(ktn + q) * 256 + col];
            }
            #pragma unroll
            for (int q4 = 0; q4 < 4; ++q4) {
                const int k = kt + (q4 << 2);
                const float4 xA = *(const float4*)&xs[2 * gg][k];
                const float4 xB = *(const float4*)&xs[2 * gg + 1][k];
                const float w0 = wv[q4 * 4 + 0], w1 = wv[q4 * 4 + 1];
                const float w2 = wv[q4 * 4 + 2], w3 = wv[q4 * 4 + 3];
                c0a = fmaf(xA.x, w0, c0a); c0a = fmaf(xA.y, w1, c0a);
                c0a = fmaf(xA.z, w2, c0a); c0a = fmaf(xA.w, w3, c0a);
                c1a = fmaf(xB.x, w0, c1a); c1a = fmaf(xB.y, w1, c1a);
                c1a = fmaf(xB.z, w2, c1a); c1a = fmaf(xB.w, w3, c1a);
            }
            if (i < 15) {
                #pragma unroll
                for (int q = 0; q < 16; ++q) wv[q] = wn[q];
            }
        }
    }
    const float b3 = b_a3[col];
    out[(size_t)rA * 256 + col] = (c0a + b3) * mask[rA];
    out[(size_t)rB * 256 + col] = (c1a + b3) * mask[rB];
}

// ---------------------------------------------------------------------------
extern "C" void kernel_launch(void* const* d_in, const int* in_sizes, int n_in,
                              void* d_out, int out_size, void* d_ws, size_t ws_size,
                              hipStream_t stream) {
    const float* v    = (const float*)d_in[0];
    const float* dist = (const float*)d_in[1];
    const float* mask = (const float*)d_in[2];
    const float* W_s1 = (const float*)d_in[3];
    const float* b_s1 = (const float*)d_in[4];
    const float* W_s2 = (const float*)d_in[5];
    const float* b_s2 = (const float*)d_in[6];
    const float* W_a1 = (const float*)d_in[7];
    const float* b_a1 = (const float*)d_in[8];
    const float* W_a2 = (const float*)d_in[9];
    const float* b_a2 = (const float*)d_in[10];
    const float* W_a3 = (const float*)d_in[11];
    const float* b_a3 = (const float*)d_in[12];
    float* out = (float*)d_out;

    char* ws = (char*)d_ws;
    float*    v1 = (float*)(ws);                   // 2 MB
    uint16_t* T  = (uint16_t*)(ws + (2u << 20));   // 2 MB bf16 [4096][256]

    prep_kernel<<<768, 512, 0, stream>>>(v, mask, W_a1, b_a1, W_s1, b_s1, W_s2, b_s2, v1, T);
    main_kernel<<<512, 512, 0, stream>>>(dist, v1, T, mask, W_a2, b_a2, W_a3, b_a3, out);
}

// Round 16
// 63.139 us; speedup vs baseline: 2.2286x; 1.5789x over previous
//
#include <hip/hip_runtime.h>
#include <hip/hip_bf16.h>
#include <cstdint>

#define LN2F 0.69314718056f

__device__ __forceinline__ float ssp(float x) {
    return fmaxf(x, 0.0f) + log1pf(expf(-fabsf(x))) - LN2F;
}

__device__ __forceinline__ uint16_t f2bf_rne(float x) {
    uint32_t u = __float_as_uint(x);
    u += 0x7FFF + ((u >> 16) & 1u);
    return (uint16_t)(u >> 16);
}

__device__ __forceinline__ float bf_lo(uint32_t u) { return __uint_as_float(u << 16); }
__device__ __forceinline__ float bf_hi(uint32_t u) { return __uint_as_float(u & 0xffff0000u); }

// ---------------------------------------------------------------------------
// prep: blocks [0,256): v1 = (m*(v@W_a1)+b_a1)*m   (8 rows/block)
//       blocks [256,512): table T[g][d] = F(g*0.005)[d] bf16 (8 g/block,
//         G=2048). Hidden layer truncated to the 25 RBF terms with
//         |d - mu_r| <= 1.25 (rest < 2e-7 -> negligible).
// ---------------------------------------------------------------------------
__global__ __launch_bounds__(512) void prep_kernel(
    const float* __restrict__ v, const float* __restrict__ mask,
    const float* __restrict__ W_a1, const float* __restrict__ b_a1,
    const float* __restrict__ W_s1, const float* __restrict__ b_s1,
    const float* __restrict__ W_s2, const float* __restrict__ b_s2,
    float* __restrict__ v1, uint16_t* __restrict__ T) {
    __shared__ float sA[8][304];
    __shared__ float sB[8][64];
    const int t = threadIdx.x;

    if (blockIdx.x < 256) {
        const int r0 = blockIdx.x * 8;
        for (int e = t; e < 2048; e += 512) {
            int row = e >> 8, c = e & 255;
            sA[row][c] = v[(r0 + row) * 256 + c];
        }
        __syncthreads();
        const int col = t & 255;
        const int g = t >> 8;
        const int c0 = blockIdx.x & 15;
        float acc[4] = {0.f, 0.f, 0.f, 0.f};
        float w[16], wn[16];
        {
            const int kt = c0 * 16;
            #pragma unroll
            for (int q = 0; q < 16; ++q) w[q] = W_a1[(kt + q) * 256 + col];
        }
        for (int i = 0; i < 16; ++i) {
            const int kt = ((c0 + i) & 15) * 16;
            if (i < 15) {
                const int ktn = ((c0 + i + 1) & 15) * 16;
                #pragma unroll
                for (int q = 0; q < 16; ++q) wn[q] = W_a1[(ktn + q) * 256 + col];
            }
            #pragma unroll
            for (int q4 = 0; q4 < 4; ++q4) {
                const int k = kt + q4 * 4;
                const float w0 = w[q4 * 4 + 0], w1 = w[q4 * 4 + 1];
                const float w2 = w[q4 * 4 + 2], w3 = w[q4 * 4 + 3];
                #pragma unroll
                for (int rr = 0; rr < 4; ++rr) {
                    const float4 xv = *(const float4*)&sA[g * 4 + rr][k];
                    float a = acc[rr];
                    a = fmaf(xv.x, w0, a);
                    a = fmaf(xv.y, w1, a);
                    a = fmaf(xv.z, w2, a);
                    a = fmaf(xv.w, w3, a);
                    acc[rr] = a;
                }
            }
            if (i < 15) {
                #pragma unroll
                for (int q = 0; q < 16; ++q) w[q] = wn[q];
            }
        }
        const float b = b_a1[col];
        #pragma unroll
        for (int rr = 0; rr < 4; ++rr) {
            const int r = r0 + g * 4 + rr;
            const float m = mask[r];
            v1[r * 256 + col] = (acc[rr] * m + b) * m;
        }
    } else {
        const int g0 = (blockIdx.x - 256) * 8;
        #pragma unroll
        for (int gg = 0; gg < 8; ++gg) {
            if (t < 300) {
                float d = (float)(g0 + gg) * 0.005f;
                float diff = d - 0.1f * (float)t;
                sA[gg][t] = expf(-10.f * diff * diff);
            }
        }
        __syncthreads();
        {   // h = ssp(rbf @ W_s1 + b_s1), truncated to 25-term window
            int gg = t >> 6, c = t & 63;
            float d = (float)(g0 + gg) * 0.005f;
            int r0w = (int)fmaf(d, 10.f, 0.5f) - 12;      // window start
            r0w = max(0, min(r0w, 275));
            float a0 = 0.f, a1 = 0.f;
            #pragma unroll
            for (int i = 0; i < 25; i += 5) {
                const int r = r0w + i;
                a0 = fmaf(sA[gg][r + 0], W_s1[(r + 0) * 64 + c], a0);
                a1 = fmaf(sA[gg][r + 1], W_s1[(r + 1) * 64 + c], a1);
                a0 = fmaf(sA[gg][r + 2], W_s1[(r + 2) * 64 + c], a0);
                a1 = fmaf(sA[gg][r + 3], W_s1[(r + 3) * 64 + c], a1);
                a0 = fmaf(sA[gg][r + 4], W_s1[(r + 4) * 64 + c], a0);
            }
            sB[gg][c] = ssp(b_s1[c] + a0 + a1);
        }
        __syncthreads();
        {
            int col = t & 255, glo = t >> 8;
            float bb = b_s2[col];
            float val[4];
            #pragma unroll
            for (int q = 0; q < 4; ++q) val[q] = bb;
            for (int c = 0; c < 64; ++c) {
                float w = W_s2[c * 256 + col];
                #pragma unroll
                for (int q = 0; q < 4; ++q)
                    val[q] = fmaf(sB[glo + 2 * q][c], w, val[q]);
            }
            #pragma unroll
            for (int q = 0; q < 4; ++q) {
                int g = g0 + glo + 2 * q;
                T[g * 256 + col] = f2bf_rne(ssp(val[q]));
            }
        }
    }
}

// ---------------------------------------------------------------------------
// main (exact R13-measured structure): 512 blocks x 512 thr, 4 rows/block,
// double-buffered v1 staging. Gather: wave w = (row = w>>1, half = w&1);
// lane l owns dims d0 = (half<<7)+2l. Disjoint dims -> no cross-wave reduce.
// Linears: col-split 2 rows/thread, W[k][col] coalesced, 16-deep prefetch.
// ---------------------------------------------------------------------------
__global__ __launch_bounds__(512) void main_kernel(
    const float* __restrict__ dist, const float* __restrict__ v1,
    const uint16_t* __restrict__ T, const float* __restrict__ mask,
    const float* __restrict__ W_a2, const float* __restrict__ b_a2,
    const float* __restrict__ W_a3, const float* __restrict__ b_a3,
    float* __restrict__ out) {
    __shared__ float v1s[2][32][256];  // 64 KB double-buffered j-tile
    __shared__ uint32_t sk[4][256];    // 4 KB table byte offsets
    __shared__ float xs[4][256];       // 4 KB activations
    const int t = threadIdx.x;
    const int r0 = blockIdx.x * 4;
    const int b = r0 >> 8;
    const int w = t >> 6;              // wave 0..7
    const int l = t & 63;
    const int row = w >> 1;            // 0..3
    const int d0 = ((w & 1) << 7) + (l << 1);   // dims d0, d0+1 (max 254)

    #pragma unroll
    for (int it = 0; it < 2; ++it) {
        int e = t + it * 512;
        int rr = e >> 8, j = e & 255;
        float d = dist[(size_t)(r0 + rr) * 256 + j];
        int k = (int)fmaf(d, 200.f, 0.5f);   // nearest grid point, step 0.005
        sk[rr][j] = (uint32_t)(min(k, 2047) << 9);
    }

    float2 acc = make_float2(0.f, 0.f);
    const char* Tp = (const char*)T + (d0 << 1);   // byte offset d0*2
    const float4* srcbase = (const float4*)(v1 + ((size_t)b << 16));

    {   // stage tile 0
        const float4* src = srcbase;
        float4* dst = (float4*)v1s[0];
        #pragma unroll
        for (int u = 0; u < 4; ++u)
            dst[u * 512 + t] = src[u * 512 + t];
    }
    __syncthreads();   // covers sk + tile 0

    for (int jt = 0; jt < 256; jt += 32) {
        const int cur = (jt >> 5) & 1;
        float4 pf[4];
        const bool more = (jt + 32) < 256;
        if (more) {   // issue next-tile loads early (hide under compute)
            const float4* src = srcbase + (jt + 32) * 64;
            #pragma unroll
            for (int u = 0; u < 4; ++u)
                pf[u] = src[u * 512 + t];
        }
        const float (*vt)[256] = v1s[cur];
        #pragma unroll 2
        for (int jj = 0; jj < 32; jj += 4) {
            const uint4 kk = *(const uint4*)&sk[row][jt + jj];
            const uint32_t u0 = *(const uint32_t*)(Tp + kk.x);
            const uint32_t u1 = *(const uint32_t*)(Tp + kk.y);
            const uint32_t u2 = *(const uint32_t*)(Tp + kk.z);
            const uint32_t u3 = *(const uint32_t*)(Tp + kk.w);
            const float2 w0 = *(const float2*)&vt[jj + 0][d0];
            const float2 w1 = *(const float2*)&vt[jj + 1][d0];
            const float2 w2 = *(const float2*)&vt[jj + 2][d0];
            const float2 w3 = *(const float2*)&vt[jj + 3][d0];
            acc.x = fmaf(bf_lo(u0), w0.x, acc.x);
            acc.y = fmaf(bf_hi(u0), w0.y, acc.y);
            acc.x = fmaf(bf_lo(u1), w1.x, acc.x);
            acc.y = fmaf(bf_hi(u1), w1.y, acc.y);
            acc.x = fmaf(bf_lo(u2), w2.x, acc.x);
            acc.y = fmaf(bf_hi(u2), w2.y, acc.y);
            acc.x = fmaf(bf_lo(u3), w3.x, acc.x);
            acc.y = fmaf(bf_hi(u3), w3.y, acc.y);
        }
        if (more) {   // write prefetched tile to alternate buffer
            float4* dst = (float4*)v1s[cur ^ 1];
            #pragma unroll
            for (int u = 0; u < 4; ++u)
                dst[u * 512 + t] = pf[u];
        }
        __syncthreads();
    }
    {   // disjoint dims per wave -> direct write, no reduce
        const float m = mask[r0 + row];
        *(float2*)&xs[row][d0] = make_float2(acc.x * m, acc.y * m);
    }
    __syncthreads();

    // ---------------- a2 then a3 (col-split, 2 rows/thread) ----------------
    const int col = t & 255;
    const int gg = t >> 8;               // rows 2gg, 2gg+1
    const int rA = r0 + 2 * gg, rB = rA + 1;
    const int c0 = blockIdx.x & 15;

    float a0 = 0.f, a1 = 0.f;
    {
        float wv[16], wn[16];
        {
            const int kt = c0 * 16;
            #pragma unroll
            for (int q = 0; q < 16; ++q) wv[q] = W_a2[(kt + q) * 256 + col];
        }
        for (int i = 0; i < 16; ++i) {
            const int kt = ((c0 + i) & 15) * 16;
            if (i < 15) {
                const int ktn = ((c0 + i + 1) & 15) * 16;
                #pragma unroll
                for (int q = 0; q < 16; ++q) wn[q] = W_a2[(ktn + q) * 256 + col];
            }
            #pragma unroll
            for (int q4 = 0; q4 < 4; ++q4) {
                const int k = kt + (q4 << 2);
                const float4 xA = *(const float4*)&xs[2 * gg][k];
                const float4 xB = *(const float4*)&xs[2 * gg + 1][k];
                const float w0 = wv[q4 * 4 + 0], w1 = wv[q4 * 4 + 1];
                const float w2 = wv[q4 * 4 + 2], w3 = wv[q4 * 4 + 3];
                a0 = fmaf(xA.x, w0, a0); a0 = fmaf(xA.y, w1, a0);
                a0 = fmaf(xA.z, w2, a0); a0 = fmaf(xA.w, w3, a0);
                a1 = fmaf(xB.x, w0, a1); a1 = fmaf(xB.y, w1, a1);
                a1 = fmaf(xB.z, w2, a1); a1 = fmaf(xB.w, w3, a1);
            }
            if (i < 15) {
                #pragma unroll
                for (int q = 0; q < 16; ++q) wv[q] = wn[q];
            }
        }
    }
    const float b2 = b_a2[col];
    const float y0 = ssp(a0 + b2) * mask[rA];
    const float y1 = ssp(a1 + b2) * mask[rB];
    __syncthreads();
    xs[2 * gg][col] = y0;
    xs[2 * gg + 1][col] = y1;
    __syncthreads();

    float c0a = 0.f, c1a = 0.f;
    {
        float wv[16], wn[16];
        {
            const int kt = c0 * 16;
            #pragma unroll
            for (int q = 0; q < 16; ++q) wv[q] = W_a3[(kt + q) * 256 + col];
        }
        for (int i = 0; i < 16; ++i) {
            const int kt = ((c0 + i) & 15) * 16;
            if (i < 15) {
                const int ktn = ((c0 + i + 1) & 15) * 16;
                #pragma unroll
                for (int q = 0; q < 16; ++q) wn[q] = W_a3[(ktn + q) * 256 + col];
            }
            #pragma unroll
            for (int q4 = 0; q4 < 4; ++q4) {
                const int k = kt + (q4 << 2);
                const float4 xA = *(const float4*)&xs[2 * gg][k];
                const float4 xB = *(const float4*)&xs[2 * gg + 1][k];
                const float w0 = wv[q4 * 4 + 0], w1 = wv[q4 * 4 + 1];
                const float w2 = wv[q4 * 4 + 2], w3 = wv[q4 * 4 + 3];
                c0a = fmaf(xA.x, w0, c0a); c0a = fmaf(xA.y, w1, c0a);
                c0a = fmaf(xA.z, w2, c0a); c0a = fmaf(xA.w, w3, c0a);
                c1a = fmaf(xB.x, w0, c1a); c1a = fmaf(xB.y, w1, c1a);
                c1a = fmaf(xB.z, w2, c1a); c1a = fmaf(xB.w, w3, c1a);
            }
            if (i < 15) {
                #pragma unroll
                for (int q = 0; q < 16; ++q) wv[q] = wn[q];
            }
        }
    }
    const float b3 = b_a3[col];
    out[(size_t)rA * 256 + col] = (c0a + b3) * mask[rA];
    out[(size_t)rB * 256 + col] = (c1a + b3) * mask[rB];
}

// ---------------------------------------------------------------------------
extern "C" void kernel_launch(void* const* d_in, const int* in_sizes, int n_in,
                              void* d_out, int out_size, void* d_ws, size_t ws_size,
                              hipStream_t stream) {
    const float* v    = (const float*)d_in[0];
    const float* dist = (const float*)d_in[1];
    const float* mask = (const float*)d_in[2];
    const float* W_s1 = (const float*)d_in[3];
    const float* b_s1 = (const float*)d_in[4];
    const float* W_s2 = (const float*)d_in[5];
    const float* b_s2 = (const float*)d_in[6];
    const float* W_a1 = (const float*)d_in[7];
    const float* b_a1 = (const float*)d_in[8];
    const float* W_a2 = (const float*)d_in[9];
    const float* b_a2 = (const float*)d_in[10];
    const float* W_a3 = (const float*)d_in[11];
    const float* b_a3 = (const float*)d_in[12];
    float* out = (float*)d_out;

    char* ws = (char*)d_ws;
    float*    v1 = (float*)(ws);                   // 2 MB
    uint16_t* T  = (uint16_t*)(ws + (2u << 20));   // 1 MB bf16 [2048][256]

    prep_kernel<<<512, 512, 0, stream>>>(v, mask, W_a1, b_a1, W_s1, b_s1, W_s2, b_s2, v1, T);
    main_kernel<<<512, 512, 0, stream>>>(dist, v1, T, mask, W_a2, b_a2, W_a3, b_a3, out);
}